// Round 4
// baseline (218.072 us; speedup 1.0000x reference)
//
#include <hip/hip_runtime.h>
#include <hip/hip_bf16.h>

using bf16 = __hip_bfloat16;
typedef __bf16 bf16x8 __attribute__((ext_vector_type(8)));
typedef short short4v __attribute__((ext_vector_type(4)));
typedef short short8v __attribute__((ext_vector_type(8)));
typedef float float4v __attribute__((ext_vector_type(4)));

#define DIM   768
#define NH    12
#define HD    64
#define SEQ   2048
#define BATCH 4
#define TOK   (BATCH * SEQ)   // 8192
// softmax scale * log2(e) folded into q at QKV epilogue (flash uses exp2)
#define SCALE_QL2E 0.18033688011112042f

#define NX  (TOK * DIM)        // 6291456
#define NWQ (3 * DIM * DIM)    // 1769472
#define NWP (DIM * DIM)        //  589824

__device__ __forceinline__ short f2bf(float f) {
  union { bf16 h; short s; } u;
  u.h = __float2bfloat16(f);
  return u.s;
}

union frag8 { short4v h[2]; short8v s; bf16x8 b; };

// global(16B) -> LDS async DMA; LDS dest must be wave-uniform base + lane*16B
__device__ __forceinline__ void async_copy16(const bf16* g, short* l) {
  __builtin_amdgcn_global_load_lds(
      (const __attribute__((address_space(1))) unsigned int*)g,
      (__attribute__((address_space(3))) unsigned int*)l, 16, 0, 0);
}

// ---------------------------------------------------------------------------
// Kernel 0: f32 -> bf16 convert for x, w_qkv, w_proj (one fused launch)
// ---------------------------------------------------------------------------
__global__ void __launch_bounds__(256)
cvt3(const float* __restrict__ a, bf16* __restrict__ oa, long na,
     const float* __restrict__ b, bf16* __restrict__ ob, long nb,
     const float* __restrict__ c, bf16* __restrict__ oc, long nc) {
  const long i = ((long)blockIdx.x * 256 + threadIdx.x) * 8;
  const float* src; bf16* dst; long off;
  if (i < na)                { src = a; dst = oa; off = i; }
  else if (i < na + nb)      { src = b; dst = ob; off = i - na; }
  else if (i < na + nb + nc) { src = c; dst = oc; off = i - na - nb; }
  else return;
  const float4v x0 = *(const float4v*)(src + off);
  const float4v x1 = *(const float4v*)(src + off + 4);
  short8v r;
  r[0] = f2bf(x0[0]); r[1] = f2bf(x0[1]); r[2] = f2bf(x0[2]); r[3] = f2bf(x0[3]);
  r[4] = f2bf(x1[0]); r[5] = f2bf(x1[1]); r[6] = f2bf(x1[2]); r[7] = f2bf(x1[3]);
  *(short8v*)(dst + off) = r;
}

// ---------------------------------------------------------------------------
// Shared 128x128 bf16 GEMM main loop (m97 structure) — still used by gemm_proj
// ---------------------------------------------------------------------------
__device__ __forceinline__ void gemm_mainloop(const bf16* __restrict__ A,
                                              const bf16* __restrict__ B,
                                              short* As, short* Bs,
                                              float4v acc[4][4]) {
  const int t = threadIdx.x;
  const int w = t >> 6, l = t & 63, lr = l & 15, q = l >> 4;
  const int wr = ((w >> 1) << 6), wc = ((w & 1) << 6);

  const bf16* Ag = A + (t >> 2) * DIM + (t & 3) * 8;
  const bf16* Bg = B + (t >> 2) * DIM + (t & 3) * 8;

  for (int k0 = 0; k0 < DIM; k0 += 32) {
    __syncthreads();                       // previous tile's consumers done
    async_copy16(Ag,            &As[t * 8]);
    async_copy16(Ag + 64 * DIM, &As[2048 + t * 8]);
    async_copy16(Bg,            &Bs[t * 8]);
    async_copy16(Bg + 64 * DIM, &Bs[2048 + t * 8]);
    Ag += 32; Bg += 32;
    __syncthreads();                       // vmcnt(0) drain before barrier

    bf16x8 af[4], bfv[4];
#pragma unroll
    for (int i = 0; i < 4; ++i)
      af[i] = *(const bf16x8*)&As[(wr + i * 16 + lr) * 32 + q * 8];
#pragma unroll
    for (int j = 0; j < 4; ++j)
      bfv[j] = *(const bf16x8*)&Bs[(wc + j * 16 + lr) * 32 + q * 8];
#pragma unroll
    for (int i = 0; i < 4; ++i)
#pragma unroll
      for (int j = 0; j < 4; ++j)
        acc[i][j] = __builtin_amdgcn_mfma_f32_16x16x32_bf16(af[i], bfv[j],
                                                            acc[i][j], 0, 0, 0);
  }
}

// ---------------------------------------------------------------------------
// Kernel 1: QKV projection — 256x256 tile, BK=64, 8 waves, 8-phase counted-
// vmcnt schedule (T1+T2+T3+T4+T5).  (unchanged this round — flash masks its
// counters; next round's top-5 should surface it.)
//
// LDS swizzle (fixed r2): fragment ds_read_b128 hits byte 64*row + 16*q.
// Row stride 64B => bank shift 16: an 8-lane b128 group (q fixed, row =
// base+lr) needs its 16B-slot index spread by row bits 1-2:
//   slot' = q ^ ((row>>1)&3)
// Lanes 0-7 start at banks {0,20,8,28,16,4,24,12} — conflict-free.
// global_load_lds writes linearly, so the same XOR is pre-applied to the
// per-lane GLOBAL source column (rule #21: both sides or neither).
// ---------------------------------------------------------------------------
#define STG(gp, c, slot, k0)                                                  \
  async_copy16((gp) + (k0),      &lds[c][slot][t * 8]);                       \
  async_copy16((gp) + (k0) + 32, &lds[c][slot][4096 + t * 8])

#define RD_A(dst, C, slot)                                                    \
  _Pragma("unroll") for (int f_ = 0; f_ < 4; ++f_) {                          \
    dst[f_][0] = *(const bf16x8*)&lds[C][slot][f_ * 1024 + arow32 + acol];    \
    dst[f_][1] = *(const bf16x8*)&lds[C][slot][4096 + f_ * 1024 + arow32 + acol]; \
  }

#define RD_B(dst, C, slot)                                                    \
  _Pragma("unroll") for (int g_ = 0; g_ < 2; ++g_) {                          \
    dst[g_][0] = *(const bf16x8*)&lds[C][slot][g_ * 2048 + brow32 + acol];    \
    dst[g_][1] = *(const bf16x8*)&lds[C][slot][4096 + g_ * 2048 + brow32 + acol]; \
  }

#define MFMA8(AF, BF, MO, NO)                                                 \
  _Pragma("unroll") for (int f_ = 0; f_ < 4; ++f_)                            \
  _Pragma("unroll") for (int g_ = 0; g_ < 2; ++g_) {                          \
    acc[(MO) + f_][(NO) + g_] = __builtin_amdgcn_mfma_f32_16x16x32_bf16(      \
        AF[f_][0], BF[g_][0], acc[(MO) + f_][(NO) + g_], 0, 0, 0);            \
    acc[(MO) + f_][(NO) + g_] = __builtin_amdgcn_mfma_f32_16x16x32_bf16(      \
        AF[f_][1], BF[g_][1], acc[(MO) + f_][(NO) + g_], 0, 0, 0);            \
  }

#define BARRIER __builtin_amdgcn_s_barrier()
#define LGKM0 asm volatile("s_waitcnt lgkmcnt(0)" ::: "memory")
#define VW6 asm volatile("s_waitcnt vmcnt(6)" ::: "memory")
#define VW0 asm volatile("s_waitcnt vmcnt(0)" ::: "memory")
#define NOSTG (void)0

#define KTILE(C, ST1, ST2, ST3, ST4, VW)                                      \
  {                                                                           \
    bf16x8 a0[4][2], a1[4][2], b0[2][2], b1[2][2];                            \
    RD_A(a0, C, 0); RD_B(b0, C, 2);                                           \
    ST1; BARRIER; LGKM0;                                                      \
    __builtin_amdgcn_s_setprio(1); MFMA8(a0, b0, 0, 0);                       \
    __builtin_amdgcn_s_setprio(0); BARRIER;                                   \
    RD_B(b1, C, 3);                                                           \
    ST2; BARRIER; LGKM0;                                                      \
    __builtin_amdgcn_s_setprio(1); MFMA8(a0, b1, 0, 2);                       \
    __builtin_amdgcn_s_setprio(0); BARRIER;                                   \
    RD_A(a1, C, 1);                                                           \
    ST3; BARRIER; LGKM0;                                                      \
    __builtin_amdgcn_s_setprio(1); MFMA8(a1, b0, 4, 0);                       \
    __builtin_amdgcn_s_setprio(0); BARRIER;                                   \
    ST4; BARRIER;                                                             \
    __builtin_amdgcn_s_setprio(1); MFMA8(a1, b1, 4, 2);                       \
    __builtin_amdgcn_s_setprio(0); VW; BARRIER;                               \
  }

__global__ void __launch_bounds__(512, 2)
gemm_qkv(const bf16* __restrict__ X, const bf16* __restrict__ W,
         const float* __restrict__ bias,
         bf16* __restrict__ qb, bf16* __restrict__ kb, bf16* __restrict__ vb) {
  __shared__ short lds[2][4][8192];   // 128 KiB
  const int t = threadIdx.x;
  const int w = t >> 6, l = t & 63, lr = l & 15, q = l >> 4;
  const int wm = w >> 2, wn = w & 3;

  // XCD-aware bijective swizzle: 288 blocks, 288 % 8 == 0, 36 blocks/XCD.
  const int orig = blockIdx.x;
  const int swz = (orig & 7) * 36 + (orig >> 3);
  const int tm = swz / 9, tn = swz - tm * 9;
  const int row0 = tm * 256, col0 = tn * 256;

  // staging coords: thread t covers half-tile row sr = t>>2, 16B-slot t&3;
  // global col pre-applies the read swizzle (key = row bits 1-2)
  const int sr = t >> 2;
  const int scol = (((t & 3) << 3) ^ (((sr >> 1) & 3) << 3));
  const bf16* pa0 = X + (size_t)(row0 +       sr) * DIM + scol;
  const bf16* pa1 = X + (size_t)(row0 + 128 + sr) * DIM + scol;
  const bf16* pb0 = W + (size_t)(col0 +       sr) * DIM + scol;
  const bf16* pb1 = W + (size_t)(col0 + 128 + sr) * DIM + scol;

  // fragment-read coords: frag row = base16 + lr, so key bits 1-2 come from
  // lr only -> per-thread constant XOR
  const int acol = ((q << 3) ^ (((lr >> 1) & 3) << 3));
  const int arow32 = (wm * 16 + lr) * 32;
  const int brow32 = (wn * 16 + lr) * 32;

  float4v acc[8][4] = {};

  // prologue: tile0 -> buf0 (all 4 slots), tile1 -> buf1 (A0,B0,B1).
  STG(pa0, 0, 0, 0);
  STG(pb0, 0, 2, 0);
  STG(pb1, 0, 3, 0);
  STG(pa1, 0, 1, 0);
  STG(pa0, 1, 0, 64);
  STG(pb0, 1, 2, 64);
  STG(pb1, 1, 3, 64);
  asm volatile("s_waitcnt vmcnt(6)" ::: "memory");
  BARRIER;

#pragma unroll 1
  for (int i = 0; i < 5; ++i) {
    KTILE(0, STG(pa1, 1, 1, 64),  STG(pa0, 0, 0, 128),
             STG(pb0, 0, 2, 128), STG(pb1, 0, 3, 128), VW6);
    KTILE(1, STG(pa1, 0, 1, 128), STG(pa0, 1, 0, 192),
             STG(pb0, 1, 2, 192), STG(pb1, 1, 3, 192), VW6);
    pa0 += 128; pa1 += 128; pb0 += 128; pb1 += 128;
  }
  KTILE(0, STG(pa1, 1, 1, 64), NOSTG, NOSTG, NOSTG, VW0);
  KTILE(1, NOSTG, NOSTG, NOSTG, NOSTG, NOSTG);

  // C-write epilogue
#pragma unroll
  for (int nf = 0; nf < 4; ++nf) {
    const int gn = col0 + nf * 64 + wn * 16 + lr;   // 0..2303
    const int which = gn / DIM;                     // uniform per 16-lane frag
    const int cc = gn - which * DIM;
    const int hh = cc >> 6, dd = cc & 63;
    const float bv = bias[gn];
#pragma unroll
    for (int mf = 0; mf < 8; ++mf) {
      const int gm0 = row0 + mf * 32 + wm * 16 + (q << 2);  // token base (x4)
      const int b = gm0 >> 11, n0 = gm0 & 2047;
      if (which == 2) {
        short4v pv;
#pragma unroll
        for (int r = 0; r < 4; ++r) pv[r] = f2bf(acc[mf][nf][r] + bv);
        *(short4v*)&vb[((size_t)(b * NH + hh) * HD + dd) * SEQ + n0] = pv;
      } else {
        bf16* dst = (which == 0) ? qb : kb;
        const float sc = (which == 0) ? SCALE_QL2E : 1.0f;
#pragma unroll
        for (int r = 0; r < 4; ++r)
          dst[((size_t)(b * NH + hh) * SEQ + n0 + r) * HD + dd] =
              __float2bfloat16((acc[mf][nf][r] + bv) * sc);
      }
    }
  }
}

// ---------------------------------------------------------------------------
// Kernel 2: flash attention — r4 restructure: KVBLK=64, double-buffered K/V,
// ONE barrier per kv-tile, l-sum via MFMA ones-trick, setprio on MFMA.
//
// r3 post-mortem: 2 barriers/kt with a pure ds_write span between them =
// ~36% idle (MfmaUtil 30 + VALUBusy 34).  With dbuf, the write of tile kt
// and the prefetch of kt+1 live in the SAME inter-barrier span as tile kt's
// compute, so they dual-issue under MFMA/VALU.  Single barrier per iter is
// safe: writers of buf[cur] at kt only run after all waves passed barrier
// kt-1, which post-dates every read of buf[cur] (last touched at kt-2).
//
// l-sum: l += P·1⃗ as 4 MFMAs/kt on the 30%-busy matrix pipe instead of 64
// VALU adds on the 34%-busy VALU pipe.  lacc C/D layout is col-replicated,
// so each lane ends holding exactly its o-rows' l — epilogue shuffles gone.
//
// LDS 34.3 KB (pads 68/66 chosen by bank model: all reads/writes <=2-way,
// which is free per m136); 3 blocks/CU, grid 768 = exactly 3*256, no tail.
// Bank conflicts in flash are DONE — remaining counter counts free 2-ways.
// (256,4) is a known trap: r2 spilled at VGPR 64 (WRITE_SIZE 12.6->280MB).
// ---------------------------------------------------------------------------
__global__ void __launch_bounds__(256, 3)
flash_attn(const bf16* __restrict__ Qp, const bf16* __restrict__ Kp,
           const bf16* __restrict__ Vtp, bf16* __restrict__ Op) {
  const int bh = blockIdx.y, qt = blockIdx.x;
  const int t = threadIdx.x, w = t >> 6, l = t & 63, lr = l & 15, q = l >> 4;
  __shared__ short Ks[2][64 * 68];   // K tile [kk][d], dbuf, pad 64->68
  __shared__ short Vt[2][64 * 66];   // V^T tile [d][kk], dbuf, pad 64->66

  const bf16* Qb = Qp  + (size_t)(bh * SEQ + qt * 128) * HD;
  const bf16* Kb = Kp  + (size_t)bh * SEQ * HD;
  const bf16* Vb = Vtp + (size_t)bh * HD * SEQ;   // [d][n]

  const int tr3 = t >> 3, td8 = (t & 7) * 8;     // 32 rows x 64 cols per pass

  // stage Q [128][64]: rows 0-63 -> Ks[0], rows 64-127 -> Ks[1]
#pragma unroll
  for (int i = 0; i < 4; ++i) {
    const int row = i * 32 + tr3;
    *(short8v*)&Ks[row >> 6][(row & 63) * 68 + td8] =
        *(const short8v*)(Qb + (size_t)row * HD + td8);
  }
  __syncthreads();
  bf16x8 qf[2][2];
#pragma unroll
  for (int it = 0; it < 2; ++it)
#pragma unroll
    for (int kq = 0; kq < 2; ++kq) {
      const int row = w * 32 + it * 16 + lr;
      qf[it][kq] = *(const bf16x8*)&Ks[row >> 6][(row & 63) * 68 + kq * 32 + q * 8];
    }
  __syncthreads();   // all Q frags in regs before kt=0 overwrites Ks[0]

  // prefetch K/V tile 0 into registers
  short8v kr[2], vr[2];
#pragma unroll
  for (int i = 0; i < 2; ++i) {
    kr[i] = *(const short8v*)(Kb + (size_t)(i * 32 + tr3) * HD + td8);
    vr[i] = *(const short8v*)(Vb + (size_t)(i * 32 + tr3) * SEQ + td8);
  }

  frag8 ones;            // all-ones bf16 B-fragment for the l row-sum MFMA
#pragma unroll
  for (int r = 0; r < 8; ++r) ones.s[r] = (short)0x3F80;

  float4v o[2][4] = {};
  float4v lacc[2] = {};  // l, col-replicated in C/D layout

  for (int kt = 0; kt < 32; ++kt) {
    const int cur = kt & 1;
    // write tile kt (regs->LDS); issue prefetch kt+1 (hides under compute)
#pragma unroll
    for (int i = 0; i < 2; ++i) {
      *(short8v*)&Ks[cur][(i * 32 + tr3) * 68 + td8] = kr[i];
      *(short8v*)&Vt[cur][(i * 32 + tr3) * 66 + td8] = vr[i];
    }
    if (kt < 31) {
      const int k1 = (kt + 1) * 64;
#pragma unroll
      for (int i = 0; i < 2; ++i) {
        kr[i] = *(const short8v*)(Kb + (size_t)(k1 + i * 32 + tr3) * HD + td8);
        vr[i] = *(const short8v*)(Vb + (size_t)(i * 32 + tr3) * SEQ + k1 + td8);
      }
    }
    __syncthreads();

    // S^T = K * Q^T : tiles [kk 4][qr 2]
    float4v s[4][2] = {};
    __builtin_amdgcn_s_setprio(1);
#pragma unroll
    for (int jn = 0; jn < 4; ++jn) {
      bf16x8 kf[2];
#pragma unroll
      for (int kq = 0; kq < 2; ++kq)
        kf[kq] = *(const bf16x8*)&Ks[cur][(jn * 16 + lr) * 68 + kq * 32 + q * 8];
#pragma unroll
      for (int it = 0; it < 2; ++it)
#pragma unroll
        for (int kq = 0; kq < 2; ++kq)
          s[jn][it] = __builtin_amdgcn_mfma_f32_16x16x32_bf16(kf[kq], qf[it][kq],
                                                              s[jn][it], 0, 0, 0);
    }
    __builtin_amdgcn_s_setprio(0);

    // p = exp2(s), pack pairs: slot (q,j) <-> kk = 32c + 16*(j>>2) + 4q + (j&3)
    frag8 pf[2][2];
#pragma unroll
    for (int it = 0; it < 2; ++it)
#pragma unroll
      for (int c4 = 0; c4 < 2; ++c4)
#pragma unroll
        for (int r = 0; r < 4; ++r) {
          pf[c4][it].s[r]     = f2bf(__builtin_amdgcn_exp2f(s[2 * c4][it][r]));
          pf[c4][it].s[4 + r] = f2bf(__builtin_amdgcn_exp2f(s[2 * c4 + 1][it][r]));
        }

    // O += P * V ; l += P * 1  (B mirrors the paired-k slot mapping)
    __builtin_amdgcn_s_setprio(1);
#pragma unroll
    for (int c4 = 0; c4 < 2; ++c4) {
#pragma unroll
      for (int dj = 0; dj < 4; ++dj) {
        frag8 vf;
        vf.h[0] = *(const short4v*)&Vt[cur][(dj * 16 + lr) * 66 + c4 * 32 + (q << 2)];
        vf.h[1] = *(const short4v*)&Vt[cur][(dj * 16 + lr) * 66 + c4 * 32 + 16 + (q << 2)];
#pragma unroll
        for (int it = 0; it < 2; ++it)
          o[it][dj] = __builtin_amdgcn_mfma_f32_16x16x32_bf16(pf[c4][it].b, vf.b,
                                                              o[it][dj], 0, 0, 0);
      }
#pragma unroll
      for (int it = 0; it < 2; ++it)
        lacc[it] = __builtin_amdgcn_mfma_f32_16x16x32_bf16(pf[c4][it].b, ones.b,
                                                           lacc[it], 0, 0, 0);
    }
    __builtin_amdgcn_s_setprio(0);
  }

  // epilogue: linv directly per lane (lacc col-replicated), no shuffles
  const int b = bh / NH, h = bh - b * NH;
#pragma unroll
  for (int it = 0; it < 2; ++it)
#pragma unroll
    for (int r = 0; r < 4; ++r) {
      const float linv = 1.0f / lacc[it][r];
      const int grow = b * SEQ + qt * 128 + w * 32 + it * 16 + (q << 2) + r;
      bf16* orow = Op + (size_t)grow * DIM + h * HD;
#pragma unroll
      for (int dj = 0; dj < 4; ++dj)
        orow[dj * 16 + lr] = __float2bfloat16(o[it][dj][r] * linv);
    }
}

// ---------------------------------------------------------------------------
// Kernel 3: output projection.  AO[8192,768](bf16) @ w_proj^T(bf16) + b -> f32
// (unchanged this round)
// ---------------------------------------------------------------------------
__global__ void __launch_bounds__(256)
gemm_proj(const bf16* __restrict__ A, const bf16* __restrict__ W,
          const float* __restrict__ bias, float* __restrict__ out) {
  __shared__ short As[128 * 32];
  __shared__ short Bs[128 * 32];
  const int t = threadIdx.x;
  const int w = t >> 6, l = t & 63, lr = l & 15, q = l >> 4;
  const int wr = ((w >> 1) << 6), wc = ((w & 1) << 6);
  const int row0 = blockIdx.y * 128, col0 = blockIdx.x * 128;

  float4v acc[4][4] = {};
  gemm_mainloop(A + row0 * DIM, W + col0 * DIM, As, Bs, acc);

#pragma unroll
  for (int j = 0; j < 4; ++j) {
    const int gn = col0 + wc + j * 16 + lr;
    const float bv = bias[gn];
#pragma unroll
    for (int i = 0; i < 4; ++i) {
#pragma unroll
      for (int r = 0; r < 4; ++r) {
        const int gm = row0 + wr + i * 16 + (q << 2) + r;
        out[(size_t)gm * DIM + gn] = acc[i][j][r] + bv;
      }
    }
  }
}

// ---------------------------------------------------------------------------
extern "C" void kernel_launch(void* const* d_in, const int* in_sizes, int n_in,
                              void* d_out, int out_size, void* d_ws, size_t ws_size,
                              hipStream_t stream) {
  const float* x      = (const float*)d_in[0];
  const float* w_qkv  = (const float*)d_in[1];
  const float* b_qkv  = (const float*)d_in[2];
  const float* w_proj = (const float*)d_in[3];
  const float* b_proj = (const float*)d_in[4];
  float* out = (float*)d_out;

  const size_t perbuf = (size_t)BATCH * NH * SEQ * HD;  // 6291456 elems
  bf16* qb  = (bf16*)d_ws;
  bf16* kb  = qb + perbuf;
  bf16* vb  = kb + perbuf;          // [B,H,64,N] transposed
  bf16* ao  = vb + perbuf;
  bf16* xb  = ao + perbuf;          // NX
  bf16* wqb = xb + (size_t)NX;      // NWQ
  bf16* wpb = wqb + (size_t)NWQ;    // NWP

  const int cvt_blocks = (NX + NWQ + NWP) / 8 / 256;   // 4224
  cvt3<<<cvt_blocks, 256, 0, stream>>>(x, xb, NX, w_qkv, wqb, NWQ, w_proj, wpb, NWP);
  gemm_qkv <<<dim3(288), 512, 0, stream>>>(xb, wqb, b_qkv, qb, kb, vb);
  flash_attn<<<dim3(SEQ / 128, BATCH * NH), 256, 0, stream>>>(qb, kb, vb, ao);
  gemm_proj <<<dim3(DIM / 128, TOK / 128),  256, 0, stream>>>(ao, wpb, b_proj, out);
}

// Round 5
// 207.849 us; speedup vs baseline: 1.0492x; 1.0492x over previous
//
#include <hip/hip_runtime.h>
#include <hip/hip_bf16.h>

using bf16 = __hip_bfloat16;
typedef __bf16 bf16x8 __attribute__((ext_vector_type(8)));
typedef short short4v __attribute__((ext_vector_type(4)));
typedef short short8v __attribute__((ext_vector_type(8)));
typedef float float4v __attribute__((ext_vector_type(4)));

#define DIM   768
#define NH    12
#define HD    64
#define SEQ   2048
#define BATCH 4
#define TOK   (BATCH * SEQ)   // 8192
// softmax scale * log2(e) folded into q at QKV epilogue (flash uses exp2)
#define SCALE_QL2E 0.18033688011112042f

#define NX  (TOK * DIM)        // 6291456
#define NWQ (3 * DIM * DIM)    // 1769472
#define NWP (DIM * DIM)        //  589824

__device__ __forceinline__ short f2bf(float f) {
  union { bf16 h; short s; } u;
  u.h = __float2bfloat16(f);
  return u.s;
}

union frag8 { short4v h[2]; short8v s; bf16x8 b; };

// global(16B) -> LDS async DMA; LDS dest must be wave-uniform base + lane*16B
__device__ __forceinline__ void async_copy16(const bf16* g, short* l) {
  __builtin_amdgcn_global_load_lds(
      (const __attribute__((address_space(1))) unsigned int*)g,
      (__attribute__((address_space(3))) unsigned int*)l, 16, 0, 0);
}
// 4B variant (partial-row staging; dest = base + lane*4B)
__device__ __forceinline__ void async_copy4(const bf16* g, short* l) {
  __builtin_amdgcn_global_load_lds(
      (const __attribute__((address_space(1))) unsigned int*)g,
      (__attribute__((address_space(3))) unsigned int*)l, 4, 0, 0);
}

// ---------------------------------------------------------------------------
// Kernel 0: f32 -> bf16 convert for x, w_qkv, w_proj (one fused launch)
// ---------------------------------------------------------------------------
__global__ void __launch_bounds__(256)
cvt3(const float* __restrict__ a, bf16* __restrict__ oa, long na,
     const float* __restrict__ b, bf16* __restrict__ ob, long nb,
     const float* __restrict__ c, bf16* __restrict__ oc, long nc) {
  const long i = ((long)blockIdx.x * 256 + threadIdx.x) * 8;
  const float* src; bf16* dst; long off;
  if (i < na)                { src = a; dst = oa; off = i; }
  else if (i < na + nb)      { src = b; dst = ob; off = i - na; }
  else if (i < na + nb + nc) { src = c; dst = oc; off = i - na - nb; }
  else return;
  const float4v x0 = *(const float4v*)(src + off);
  const float4v x1 = *(const float4v*)(src + off + 4);
  short8v r;
  r[0] = f2bf(x0[0]); r[1] = f2bf(x0[1]); r[2] = f2bf(x0[2]); r[3] = f2bf(x0[3]);
  r[4] = f2bf(x1[0]); r[5] = f2bf(x1[1]); r[6] = f2bf(x1[2]); r[7] = f2bf(x1[3]);
  *(short8v*)(dst + off) = r;
}

// ---------------------------------------------------------------------------
// Shared 128x128 bf16 GEMM main loop (m97 structure) — still used by gemm_proj
// ---------------------------------------------------------------------------
__device__ __forceinline__ void gemm_mainloop(const bf16* __restrict__ A,
                                              const bf16* __restrict__ B,
                                              short* As, short* Bs,
                                              float4v acc[4][4]) {
  const int t = threadIdx.x;
  const int w = t >> 6, l = t & 63, lr = l & 15, q = l >> 4;
  const int wr = ((w >> 1) << 6), wc = ((w & 1) << 6);

  const bf16* Ag = A + (t >> 2) * DIM + (t & 3) * 8;
  const bf16* Bg = B + (t >> 2) * DIM + (t & 3) * 8;

  for (int k0 = 0; k0 < DIM; k0 += 32) {
    __syncthreads();                       // previous tile's consumers done
    async_copy16(Ag,            &As[t * 8]);
    async_copy16(Ag + 64 * DIM, &As[2048 + t * 8]);
    async_copy16(Bg,            &Bs[t * 8]);
    async_copy16(Bg + 64 * DIM, &Bs[2048 + t * 8]);
    Ag += 32; Bg += 32;
    __syncthreads();                       // vmcnt(0) drain before barrier

    bf16x8 af[4], bfv[4];
#pragma unroll
    for (int i = 0; i < 4; ++i)
      af[i] = *(const bf16x8*)&As[(wr + i * 16 + lr) * 32 + q * 8];
#pragma unroll
    for (int j = 0; j < 4; ++j)
      bfv[j] = *(const bf16x8*)&Bs[(wc + j * 16 + lr) * 32 + q * 8];
#pragma unroll
    for (int i = 0; i < 4; ++i)
#pragma unroll
      for (int j = 0; j < 4; ++j)
        acc[i][j] = __builtin_amdgcn_mfma_f32_16x16x32_bf16(af[i], bfv[j],
                                                            acc[i][j], 0, 0, 0);
  }
}

// ---------------------------------------------------------------------------
// Kernel 1: QKV projection — r5 GRID FIX.  r4 post-mortem: the 288-block
// 256x256 grid at 1 block/CU is a 2-round makespan (round 2 = 32/256 CUs)
// -> 56% efficiency cap no matter the inner loop.  New: tile 256x288
// (2304 = 8*288), grid 32x8 = EXACTLY 256 blocks, one round, all CUs busy.
//
// Inner loop: 24 K-panel phases (BK=32) on a 3-slot LDS ring (A 16KB +
// B 18KB per slot, 102KB total, 1 block/CU).  Per phase:
//   {4+9 ds_read_b128 | stage panel k+2 (5 loads) | barrier | lgkm0 |
//    setprio(1) 36 MFMA setprio(0) | vmcnt(5) | barrier}
// vmcnt(5): in-flight = panels k+1,k+2 (5 loads each, uniform per wave);
// retire exactly panel k+1, keep k+2 flying — never drain to 0 (T4).
// Ring-3 WAR safety: stage of panel k+2 overwrites slot((k+2)%3) = panel
// k-1, whose ds_reads completed before the previous barrier (each wave's
// lgkm0 precedes its MFMA precedes the barrier).
//
// Wave grid 4M x 2N: wave = 64 rows x 144 cols = 4 A-frags x 9 B-frags,
// 36 MFMA/phase.  acc[4][9] = 144 VGPR; bound (512,2) -> 256 budget.
//
// LDS swizzle (r2-verified): panel [row][32] row-stride 64B; 16B-slot index
// XOR row bits 1-2 (key = ((row>>1)&3)<<3 shorts), pre-applied to the
// per-lane GLOBAL source col (rule #21).  B's partial 3rd load uses 4B DMA
// (dest base + lane*4B linear; source carries the same key).
// ---------------------------------------------------------------------------
#define VW5 asm volatile("s_waitcnt vmcnt(5)" ::: "memory")
#define VW0 asm volatile("s_waitcnt vmcnt(0)" ::: "memory")
#define BARRIER __builtin_amdgcn_s_barrier()
#define LGKM0 asm volatile("s_waitcnt lgkmcnt(0)" ::: "memory")
#define NOSTG (void)0
#define NOVW  (void)0

#define STGP(s, p)                                                            \
  async_copy16(pa + (p) * 32,             &As[s][t * 8]);                     \
  async_copy16(pa + 128 * DIM + (p) * 32, &As[s][4096 + t * 8]);              \
  async_copy16(pb + (p) * 32,             &Bs[s][t * 8]);                     \
  async_copy16(pb + 128 * DIM + (p) * 32, &Bs[s][4096 + t * 8]);              \
  async_copy4 (pb3 + (p) * 32,            &Bs[s][8192 + t * 2])

#define PHASE(RS, STG_, VW_) {                                                \
  bf16x8 af[4], bfv[9];                                                       \
  _Pragma("unroll") for (int mf_ = 0; mf_ < 4; ++mf_)                         \
    af[mf_] = *(const bf16x8*)&As[RS][mf_ * 512 + arow];                      \
  _Pragma("unroll") for (int nf_ = 0; nf_ < 9; ++nf_)                         \
    bfv[nf_] = *(const bf16x8*)&Bs[RS][nf_ * 512 + brow];                     \
  STG_; BARRIER; LGKM0;                                                       \
  __builtin_amdgcn_s_setprio(1);                                              \
  _Pragma("unroll") for (int mf_ = 0; mf_ < 4; ++mf_)                         \
  _Pragma("unroll") for (int nf_ = 0; nf_ < 9; ++nf_)                         \
    acc[mf_][nf_] = __builtin_amdgcn_mfma_f32_16x16x32_bf16(                  \
        af[mf_], bfv[nf_], acc[mf_][nf_], 0, 0, 0);                           \
  __builtin_amdgcn_s_setprio(0); VW_; BARRIER; }

__global__ void __launch_bounds__(512, 2)
gemm_qkv(const bf16* __restrict__ X, const bf16* __restrict__ W,
         const float* __restrict__ bias,
         bf16* __restrict__ qb, bf16* __restrict__ kb, bf16* __restrict__ vb) {
  __shared__ short As[3][256 * 32];   // 3 x 16 KB
  __shared__ short Bs[3][288 * 32];   // 3 x 18 KB   (total 102 KB)
  const int t = threadIdx.x;
  const int w = t >> 6, l = t & 63, lr = l & 15, q = l >> 4;
  const int wm = w >> 1, wn = w & 1;          // 4M x 2N wave grid

  // XCD-aware bijective swizzle: 256 blocks, 32/XCD; row-major decode ->
  // each XCD owns 4 consecutive M-rows x all 8 N-cols (A-panel L2 reuse).
  const int orig = blockIdx.x;
  const int swz = (orig & 7) * 32 + (orig >> 3);
  const int tm = swz >> 3, tn = swz & 7;
  const int row0 = tm * 256, col0 = tn * 288;

  // staging coords (16B loads): row sr = t>>2, 16B-slot t&3, source col
  // pre-swizzled by key(row) = row bits 1-2
  const int sr = t >> 2;
  const int scol = (((t & 3) << 3) ^ (((sr >> 1) & 3) << 3));
  const bf16* pa  = X + (size_t)(row0 + sr) * DIM + scol;
  const bf16* pb  = W + (size_t)(col0 + sr) * DIM + scol;
  // B partial 3rd load (rows 256..287, 4B DMA): row = 256 + (t>>4)
  const int r3 = 256 + (t >> 4);
  const int c3 = ((t & 15) << 1) ^ (((r3 >> 1) & 3) << 3);
  const bf16* pb3 = W + (size_t)(col0 + r3) * DIM + c3;

  // fragment-read coords: frag row = 16*base + lr -> key from lr only
  const int acol = ((q << 3) ^ (((lr >> 1) & 3) << 3));
  const int arow = (wm * 64 + lr) * 32 + acol;    // + mf*512
  const int brow = (wn * 144 + lr) * 32 + acol;   // + nf*512

  float4v acc[4][9] = {};

  // prologue: panels 0,1 -> slots 0,1 (10 loads); retire panel 0 (vmcnt 5)
  STGP(0, 0);
  STGP(1, 1);
  VW5; BARRIER;

  // 24 phases: read slot k%3, stage panel k+2 -> slot (k+2)%3
  PHASE(0, STGP(2, 2),  VW5)   // k=0
  PHASE(1, STGP(0, 3),  VW5)
  PHASE(2, STGP(1, 4),  VW5)
  PHASE(0, STGP(2, 5),  VW5)
  PHASE(1, STGP(0, 6),  VW5)
  PHASE(2, STGP(1, 7),  VW5)
  PHASE(0, STGP(2, 8),  VW5)
  PHASE(1, STGP(0, 9),  VW5)
  PHASE(2, STGP(1, 10), VW5)
  PHASE(0, STGP(2, 11), VW5)
  PHASE(1, STGP(0, 12), VW5)
  PHASE(2, STGP(1, 13), VW5)
  PHASE(0, STGP(2, 14), VW5)
  PHASE(1, STGP(0, 15), VW5)
  PHASE(2, STGP(1, 16), VW5)
  PHASE(0, STGP(2, 17), VW5)
  PHASE(1, STGP(0, 18), VW5)
  PHASE(2, STGP(1, 19), VW5)
  PHASE(0, STGP(2, 20), VW5)
  PHASE(1, STGP(0, 21), VW5)
  PHASE(2, STGP(1, 22), VW5)
  PHASE(0, STGP(2, 23), VW5)   // k=21, last stage
  PHASE(1, NOSTG,       VW0)   // k=22, drain panel 23
  PHASE(2, NOSTG,       NOVW)  // k=23

  // C-write epilogue: rows row0 + wm*64 + mf*16 + q*4 + r ;
  // cols col0 + wn*144 + nf*16 + lr.  q/k/v scatter per 16-col frag.
#pragma unroll
  for (int nf = 0; nf < 9; ++nf) {
    const int gn = col0 + wn * 144 + nf * 16 + lr;   // 0..2303
    const int which = gn / DIM;                      // uniform per frag
    const int cc = gn - which * DIM;
    const int hh = cc >> 6, dd = cc & 63;
    const float bv = bias[gn];
#pragma unroll
    for (int mf = 0; mf < 4; ++mf) {
      const int gm0 = row0 + wm * 64 + mf * 16 + (q << 2);  // token base (x4)
      const int b = gm0 >> 11, n0 = gm0 & 2047;
      if (which == 2) {
        short4v pv;
#pragma unroll
        for (int r = 0; r < 4; ++r) pv[r] = f2bf(acc[mf][nf][r] + bv);
        *(short4v*)&vb[((size_t)(b * NH + hh) * HD + dd) * SEQ + n0] = pv;
      } else {
        bf16* dst = (which == 0) ? qb : kb;
        const float sc = (which == 0) ? SCALE_QL2E : 1.0f;
#pragma unroll
        for (int r = 0; r < 4; ++r)
          dst[((size_t)(b * NH + hh) * SEQ + n0 + r) * HD + dd] =
              __float2bfloat16((acc[mf][nf][r] + bv) * sc);
      }
    }
  }
}

// ---------------------------------------------------------------------------
// Kernel 2: flash attention — r4 structure: KVBLK=64, double-buffered K/V,
// one barrier per kv-tile, l-sum via MFMA ones-trick, setprio on MFMA.
// (frozen this round to isolate the qkv grid change; 66 us = 780 TF eff.)
// ---------------------------------------------------------------------------
__global__ void __launch_bounds__(256, 3)
flash_attn(const bf16* __restrict__ Qp, const bf16* __restrict__ Kp,
           const bf16* __restrict__ Vtp, bf16* __restrict__ Op) {
  const int bh = blockIdx.y, qt = blockIdx.x;
  const int t = threadIdx.x, w = t >> 6, l = t & 63, lr = l & 15, q = l >> 4;
  __shared__ short Ks[2][64 * 68];   // K tile [kk][d], dbuf, pad 64->68
  __shared__ short Vt[2][64 * 66];   // V^T tile [d][kk], dbuf, pad 64->66

  const bf16* Qb = Qp  + (size_t)(bh * SEQ + qt * 128) * HD;
  const bf16* Kb = Kp  + (size_t)bh * SEQ * HD;
  const bf16* Vb = Vtp + (size_t)bh * HD * SEQ;   // [d][n]

  const int tr3 = t >> 3, td8 = (t & 7) * 8;     // 32 rows x 64 cols per pass

  // stage Q [128][64]: rows 0-63 -> Ks[0], rows 64-127 -> Ks[1]
#pragma unroll
  for (int i = 0; i < 4; ++i) {
    const int row = i * 32 + tr3;
    *(short8v*)&Ks[row >> 6][(row & 63) * 68 + td8] =
        *(const short8v*)(Qb + (size_t)row * HD + td8);
  }
  __syncthreads();
  bf16x8 qf[2][2];
#pragma unroll
  for (int it = 0; it < 2; ++it)
#pragma unroll
    for (int kq = 0; kq < 2; ++kq) {
      const int row = w * 32 + it * 16 + lr;
      qf[it][kq] = *(const bf16x8*)&Ks[row >> 6][(row & 63) * 68 + kq * 32 + q * 8];
    }
  __syncthreads();   // all Q frags in regs before kt=0 overwrites Ks[0]

  // prefetch K/V tile 0 into registers
  short8v kr[2], vr[2];
#pragma unroll
  for (int i = 0; i < 2; ++i) {
    kr[i] = *(const short8v*)(Kb + (size_t)(i * 32 + tr3) * HD + td8);
    vr[i] = *(const short8v*)(Vb + (size_t)(i * 32 + tr3) * SEQ + td8);
  }

  frag8 ones;            // all-ones bf16 B-fragment for the l row-sum MFMA
#pragma unroll
  for (int r = 0; r < 8; ++r) ones.s[r] = (short)0x3F80;

  float4v o[2][4] = {};
  float4v lacc[2] = {};  // l, col-replicated in C/D layout

  for (int kt = 0; kt < 32; ++kt) {
    const int cur = kt & 1;
    // write tile kt (regs->LDS); issue prefetch kt+1 (hides under compute)
#pragma unroll
    for (int i = 0; i < 2; ++i) {
      *(short8v*)&Ks[cur][(i * 32 + tr3) * 68 + td8] = kr[i];
      *(short8v*)&Vt[cur][(i * 32 + tr3) * 66 + td8] = vr[i];
    }
    if (kt < 31) {
      const int k1 = (kt + 1) * 64;
#pragma unroll
      for (int i = 0; i < 2; ++i) {
        kr[i] = *(const short8v*)(Kb + (size_t)(k1 + i * 32 + tr3) * HD + td8);
        vr[i] = *(const short8v*)(Vb + (size_t)(i * 32 + tr3) * SEQ + k1 + td8);
      }
    }
    __syncthreads();

    // S^T = K * Q^T : tiles [kk 4][qr 2]
    float4v s[4][2] = {};
    __builtin_amdgcn_s_setprio(1);
#pragma unroll
    for (int jn = 0; jn < 4; ++jn) {
      bf16x8 kf[2];
#pragma unroll
      for (int kq = 0; kq < 2; ++kq)
        kf[kq] = *(const bf16x8*)&Ks[cur][(jn * 16 + lr) * 68 + kq * 32 + q * 8];
#pragma unroll
      for (int it = 0; it < 2; ++it)
#pragma unroll
        for (int kq = 0; kq < 2; ++kq)
          s[jn][it] = __builtin_amdgcn_mfma_f32_16x16x32_bf16(kf[kq], qf[it][kq],
                                                              s[jn][it], 0, 0, 0);
    }
    __builtin_amdgcn_s_setprio(0);

    // p = exp2(s), pack pairs: slot (q,j) <-> kk = 32c + 16*(j>>2) + 4q + (j&3)
    frag8 pf[2][2];
#pragma unroll
    for (int it = 0; it < 2; ++it)
#pragma unroll
      for (int c4 = 0; c4 < 2; ++c4)
#pragma unroll
        for (int r = 0; r < 4; ++r) {
          pf[c4][it].s[r]     = f2bf(__builtin_amdgcn_exp2f(s[2 * c4][it][r]));
          pf[c4][it].s[4 + r] = f2bf(__builtin_amdgcn_exp2f(s[2 * c4 + 1][it][r]));
        }

    // O += P * V ; l += P * 1  (B mirrors the paired-k slot mapping)
    __builtin_amdgcn_s_setprio(1);
#pragma unroll
    for (int c4 = 0; c4 < 2; ++c4) {
#pragma unroll
      for (int dj = 0; dj < 4; ++dj) {
        frag8 vf;
        vf.h[0] = *(const short4v*)&Vt[cur][(dj * 16 + lr) * 66 + c4 * 32 + (q << 2)];
        vf.h[1] = *(const short4v*)&Vt[cur][(dj * 16 + lr) * 66 + c4 * 32 + 16 + (q << 2)];
#pragma unroll
        for (int it = 0; it < 2; ++it)
          o[it][dj] = __builtin_amdgcn_mfma_f32_16x16x32_bf16(pf[c4][it].b, vf.b,
                                                              o[it][dj], 0, 0, 0);
      }
#pragma unroll
      for (int it = 0; it < 2; ++it)
        lacc[it] = __builtin_amdgcn_mfma_f32_16x16x32_bf16(pf[c4][it].b, ones.b,
                                                           lacc[it], 0, 0, 0);
    }
    __builtin_amdgcn_s_setprio(0);
  }

  // epilogue: linv directly per lane (lacc col-replicated), no shuffles
  const int b = bh / NH, h = bh - b * NH;
#pragma unroll
  for (int it = 0; it < 2; ++it)
#pragma unroll
    for (int r = 0; r < 4; ++r) {
      const float linv = 1.0f / lacc[it][r];
      const int grow = b * SEQ + qt * 128 + w * 32 + it * 16 + (q << 2) + r;
      bf16* orow = Op + (size_t)grow * DIM + h * HD;
#pragma unroll
      for (int dj = 0; dj < 4; ++dj)
        orow[dj * 16 + lr] = __float2bfloat16(o[it][dj][r] * linv);
    }
}

// ---------------------------------------------------------------------------
// Kernel 3: output projection.  AO[8192,768](bf16) @ w_proj^T(bf16) + b -> f32
// (unchanged this round)
// ---------------------------------------------------------------------------
__global__ void __launch_bounds__(256)
gemm_proj(const bf16* __restrict__ A, const bf16* __restrict__ W,
          const float* __restrict__ bias, float* __restrict__ out) {
  __shared__ short As[128 * 32];
  __shared__ short Bs[128 * 32];
  const int t = threadIdx.x;
  const int w = t >> 6, l = t & 63, lr = l & 15, q = l >> 4;
  const int wr = ((w >> 1) << 6), wc = ((w & 1) << 6);
  const int row0 = blockIdx.y * 128, col0 = blockIdx.x * 128;

  float4v acc[4][4] = {};
  gemm_mainloop(A + row0 * DIM, W + col0 * DIM, As, Bs, acc);

#pragma unroll
  for (int j = 0; j < 4; ++j) {
    const int gn = col0 + wc + j * 16 + lr;
    const float bv = bias[gn];
#pragma unroll
    for (int i = 0; i < 4; ++i) {
#pragma unroll
      for (int r = 0; r < 4; ++r) {
        const int gm = row0 + wr + i * 16 + (q << 2) + r;
        out[(size_t)gm * DIM + gn] = acc[i][j][r] + bv;
      }
    }
  }
}

// ---------------------------------------------------------------------------
extern "C" void kernel_launch(void* const* d_in, const int* in_sizes, int n_in,
                              void* d_out, int out_size, void* d_ws, size_t ws_size,
                              hipStream_t stream) {
  const float* x      = (const float*)d_in[0];
  const float* w_qkv  = (const float*)d_in[1];
  const float* b_qkv  = (const float*)d_in[2];
  const float* w_proj = (const float*)d_in[3];
  const float* b_proj = (const float*)d_in[4];
  float* out = (float*)d_out;

  const size_t perbuf = (size_t)BATCH * NH * SEQ * HD;  // 6291456 elems
  bf16* qb  = (bf16*)d_ws;
  bf16* kb  = qb + perbuf;
  bf16* vb  = kb + perbuf;          // [B,H,64,N] transposed
  bf16* ao  = vb + perbuf;
  bf16* xb  = ao + perbuf;          // NX
  bf16* wqb = xb + (size_t)NX;      // NWQ
  bf16* wpb = wqb + (size_t)NWQ;    // NWP

  const int cvt_blocks = (NX + NWQ + NWP) / 8 / 256;   // 4224
  cvt3<<<cvt_blocks, 256, 0, stream>>>(x, xb, NX, w_qkv, wqb, NWQ, w_proj, wpb, NWP);
  gemm_qkv <<<dim3(256), 512, 0, stream>>>(xb, wqb, b_qkv, qb, kb, vb);
  flash_attn<<<dim3(SEQ / 128, BATCH * NH), 256, 0, stream>>>(qb, kb, vb, ao);
  gemm_proj <<<dim3(DIM / 128, TOK / 128),  256, 0, stream>>>(ao, wpb, b_proj, out);
}

// Round 6
// 205.850 us; speedup vs baseline: 1.0594x; 1.0097x over previous
//
#include <hip/hip_runtime.h>
#include <hip/hip_bf16.h>

using bf16 = __hip_bfloat16;
typedef __bf16 bf16x8 __attribute__((ext_vector_type(8)));
typedef short short4v __attribute__((ext_vector_type(4)));
typedef short short8v __attribute__((ext_vector_type(8)));
typedef float float4v __attribute__((ext_vector_type(4)));

#define DIM   768
#define NH    12
#define HD    64
#define SEQ   2048
#define BATCH 4
#define TOK   (BATCH * SEQ)   // 8192
// softmax scale * log2(e) folded into q at QKV epilogue (flash uses exp2)
#define SCALE_QL2E 0.18033688011112042f

#define NX  (TOK * DIM)        // 6291456
#define NWQ (3 * DIM * DIM)    // 1769472
#define NWP (DIM * DIM)        //  589824

__device__ __forceinline__ short f2bf(float f) {
  union { bf16 h; short s; } u;
  u.h = __float2bfloat16(f);
  return u.s;
}

union frag8 { short4v h[2]; short8v s; bf16x8 b; };

// global(16B) -> LDS async DMA; LDS dest must be wave-uniform base + lane*16B
__device__ __forceinline__ void async_copy16(const bf16* g, short* l) {
  __builtin_amdgcn_global_load_lds(
      (const __attribute__((address_space(1))) unsigned int*)g,
      (__attribute__((address_space(3))) unsigned int*)l, 16, 0, 0);
}
// 4B variant (partial-row staging; dest = base + lane*4B)
__device__ __forceinline__ void async_copy4(const bf16* g, short* l) {
  __builtin_amdgcn_global_load_lds(
      (const __attribute__((address_space(1))) unsigned int*)g,
      (__attribute__((address_space(3))) unsigned int*)l, 4, 0, 0);
}

// ---------------------------------------------------------------------------
// Kernel 0: f32 -> bf16 convert for x, w_qkv, w_proj (one fused launch)
// ---------------------------------------------------------------------------
__global__ void __launch_bounds__(256)
cvt3(const float* __restrict__ a, bf16* __restrict__ oa, long na,
     const float* __restrict__ b, bf16* __restrict__ ob, long nb,
     const float* __restrict__ c, bf16* __restrict__ oc, long nc) {
  const long i = ((long)blockIdx.x * 256 + threadIdx.x) * 8;
  const float* src; bf16* dst; long off;
  if (i < na)                { src = a; dst = oa; off = i; }
  else if (i < na + nb)      { src = b; dst = ob; off = i - na; }
  else if (i < na + nb + nc) { src = c; dst = oc; off = i - na - nb; }
  else return;
  const float4v x0 = *(const float4v*)(src + off);
  const float4v x1 = *(const float4v*)(src + off + 4);
  short8v r;
  r[0] = f2bf(x0[0]); r[1] = f2bf(x0[1]); r[2] = f2bf(x0[2]); r[3] = f2bf(x0[3]);
  r[4] = f2bf(x1[0]); r[5] = f2bf(x1[1]); r[6] = f2bf(x1[2]); r[7] = f2bf(x1[3]);
  *(short8v*)(dst + off) = r;
}

// ---------------------------------------------------------------------------
// Shared 128x128 bf16 GEMM main loop (m97 structure) — still used by gemm_proj
// ---------------------------------------------------------------------------
__device__ __forceinline__ void gemm_mainloop(const bf16* __restrict__ A,
                                              const bf16* __restrict__ B,
                                              short* As, short* Bs,
                                              float4v acc[4][4]) {
  const int t = threadIdx.x;
  const int w = t >> 6, l = t & 63, lr = l & 15, q = l >> 4;
  const int wr = ((w >> 1) << 6), wc = ((w & 1) << 6);

  const bf16* Ag = A + (t >> 2) * DIM + (t & 3) * 8;
  const bf16* Bg = B + (t >> 2) * DIM + (t & 3) * 8;

  for (int k0 = 0; k0 < DIM; k0 += 32) {
    __syncthreads();                       // previous tile's consumers done
    async_copy16(Ag,            &As[t * 8]);
    async_copy16(Ag + 64 * DIM, &As[2048 + t * 8]);
    async_copy16(Bg,            &Bs[t * 8]);
    async_copy16(Bg + 64 * DIM, &Bs[2048 + t * 8]);
    Ag += 32; Bg += 32;
    __syncthreads();                       // vmcnt(0) drain before barrier

    bf16x8 af[4], bfv[4];
#pragma unroll
    for (int i = 0; i < 4; ++i)
      af[i] = *(const bf16x8*)&As[(wr + i * 16 + lr) * 32 + q * 8];
#pragma unroll
    for (int j = 0; j < 4; ++j)
      bfv[j] = *(const bf16x8*)&Bs[(wc + j * 16 + lr) * 32 + q * 8];
#pragma unroll
    for (int i = 0; i < 4; ++i)
#pragma unroll
      for (int j = 0; j < 4; ++j)
        acc[i][j] = __builtin_amdgcn_mfma_f32_16x16x32_bf16(af[i], bfv[j],
                                                            acc[i][j], 0, 0, 0);
  }
}

// ---------------------------------------------------------------------------
// Kernel 1: QKV projection — r6: 128x288 tile, 512 blocks = 2 blocks/CU
// (one round, AND block-level overlap).
//
// r5 post-mortem: one-round grid was right, but 1 block/CU left all 8 waves
// barrier-locked through {LDS-drain -> MFMA} with nothing to fill the gaps
// (per-CU rate 2.2 TF vs the KTILE structure's 3.4).  m97's 874 TF came
// from 2-3 INDEPENDENT blocks/CU covering each other's stalls.  This round:
// 512 blocks x 256 thr (4 waves), dbuf-2 LDS = 52 KB -> 2 blocks/CU
// guaranteed (ring-3's 78 KB is one reserved byte away from an occupancy
// cliff — not worth it).  vmcnt drains to 0 per phase (dbuf-2 forces it)
// but AFTER the MFMA cluster, and the co-resident block covers the drain.
//
// Per phase (24 = K/32): {13 ds_read_b128 | stage panel k+1 (8 loads) |
// barrier | lgkm0 | setprio(1) 36 MFMA setprio(0) | vmcnt(0) | barrier}.
// Wave grid 2M x 2N: wave = 64 rows x 144 cols = 4 A-frags x 9 B-frags,
// acc[4][9] = 144 VGPR, bound (256,2) -> 256 budget.
//
// LDS swizzle (r2-verified): panel [row][32] row-stride 64B; 16B-slot index
// XOR row bits 1-2, pre-applied to per-lane GLOBAL source col (rule #21).
// All staging row-offsets are multiples of 16 -> key(row)=key(lr) invariant.
// ---------------------------------------------------------------------------
#define VW0 asm volatile("s_waitcnt vmcnt(0)" ::: "memory")
#define BARRIER __builtin_amdgcn_s_barrier()
#define LGKM0 asm volatile("s_waitcnt lgkmcnt(0)" ::: "memory")
#define NOSTG (void)0
#define NOVW  (void)0

#define STGP(s, p)                                                            \
  async_copy16(pa + (p) * 32,             &As[s][t * 8]);                     \
  async_copy16(pa + 64 * DIM + (p) * 32,  &As[s][2048 + t * 8]);              \
  async_copy16(pb + (p) * 32,             &Bs[s][t * 8]);                     \
  async_copy16(pb + 64 * DIM + (p) * 32,  &Bs[s][2048 + t * 8]);              \
  async_copy16(pb + 128 * DIM + (p) * 32, &Bs[s][4096 + t * 8]);              \
  async_copy16(pb + 192 * DIM + (p) * 32, &Bs[s][6144 + t * 8]);              \
  async_copy4 (pb3 + (p) * 32,            &Bs[s][8192 + t * 2]);              \
  async_copy4 (pb3 + 16 * DIM + (p) * 32, &Bs[s][8704 + t * 2])

#define PHASE(CUR, STG_, VW_) {                                               \
  bf16x8 af[4], bfv[9];                                                       \
  _Pragma("unroll") for (int mf_ = 0; mf_ < 4; ++mf_)                         \
    af[mf_] = *(const bf16x8*)&As[CUR][mf_ * 512 + arow];                     \
  _Pragma("unroll") for (int nf_ = 0; nf_ < 9; ++nf_)                         \
    bfv[nf_] = *(const bf16x8*)&Bs[CUR][nf_ * 512 + brow];                    \
  STG_; BARRIER; LGKM0;                                                       \
  __builtin_amdgcn_s_setprio(1);                                              \
  _Pragma("unroll") for (int mf_ = 0; mf_ < 4; ++mf_)                         \
  _Pragma("unroll") for (int nf_ = 0; nf_ < 9; ++nf_)                         \
    acc[mf_][nf_] = __builtin_amdgcn_mfma_f32_16x16x32_bf16(                  \
        af[mf_], bfv[nf_], acc[mf_][nf_], 0, 0, 0);                           \
  __builtin_amdgcn_s_setprio(0); VW_; BARRIER; }

__global__ void __launch_bounds__(256, 2)
gemm_qkv(const bf16* __restrict__ X, const bf16* __restrict__ W,
         const float* __restrict__ bias,
         bf16* __restrict__ qb, bf16* __restrict__ kb, bf16* __restrict__ vb) {
  __shared__ short As[2][128 * 32];   // 2 x 8 KB
  __shared__ short Bs[2][288 * 32];   // 2 x 18 KB   (total 52 KB, 2 blk/CU)
  const int t = threadIdx.x;
  const int w = t >> 6, l = t & 63, lr = l & 15, q = l >> 4;
  const int wm = w >> 1, wn = w & 1;          // 2M x 2N wave grid

  // XCD-aware bijective swizzle: 512 blocks, 64/XCD; each XCD owns 8
  // consecutive M-rows x all 8 N-cols (A-panel + W L2 reuse).
  const int orig = blockIdx.x;
  const int swz = (orig & 7) * 64 + (orig >> 3);
  const int tm = swz >> 3, tn = swz & 7;
  const int row0 = tm * 128, col0 = tn * 288;

  // staging coords (16B loads cover 64 rows: 256 thr x 16B = 4 KB):
  // row sr = t>>2, 16B-slot t&3, source col pre-swizzled by key(row bits 1-2)
  const int sr = t >> 2;
  const int scol = (((t & 3) << 3) ^ (((sr >> 1) & 3) << 3));
  const bf16* pa  = X + (size_t)(row0 + sr) * DIM + scol;
  const bf16* pb  = W + (size_t)(col0 + sr) * DIM + scol;
  // B rows 256..287 via 4B DMA (256 thr x 4B = 1 KB = 16 rows per load)
  const int r3 = t >> 4;
  const int c3 = ((t & 15) << 1) ^ (((r3 >> 1) & 3) << 3);
  const bf16* pb3 = W + (size_t)(col0 + 256 + r3) * DIM + c3;

  // fragment-read coords: frag row = 16*base + lr -> key from lr only
  const int acol = ((q << 3) ^ (((lr >> 1) & 3) << 3));
  const int arow = (wm * 64 + lr) * 32 + acol;    // + mf*512
  const int brow = (wn * 144 + lr) * 32 + acol;   // + nf*512

  float4v acc[4][9] = {};

  // prologue: panel 0 -> slot 0; drain own DMA, barrier for cross-wave vis
  STGP(0, 0);
  VW0; BARRIER;

  // 24 phases: read slot k&1, stage panel k+1 -> slot (k+1)&1
#pragma unroll 1
  for (int k = 0; k < 22; k += 2) {
    PHASE(0, STGP(1, k + 1), VW0)
    PHASE(1, STGP(0, k + 2), VW0)
  }
  PHASE(0, STGP(1, 23), VW0)   // k=22
  PHASE(1, NOSTG,       NOVW)  // k=23

  // C-write epilogue: rows row0 + wm*64 + mf*16 + q*4 + r ;
  // cols col0 + wn*144 + nf*16 + lr.  q/k/v scatter per 16-col frag.
#pragma unroll
  for (int nf = 0; nf < 9; ++nf) {
    const int gn = col0 + wn * 144 + nf * 16 + lr;   // 0..2303
    const int which = gn / DIM;                      // uniform per frag
    const int cc = gn - which * DIM;
    const int hh = cc >> 6, dd = cc & 63;
    const float bv = bias[gn];
#pragma unroll
    for (int mf = 0; mf < 4; ++mf) {
      const int gm0 = row0 + wm * 64 + mf * 16 + (q << 2);  // token base (x4)
      const int b = gm0 >> 11, n0 = gm0 & 2047;
      if (which == 2) {
        short4v pv;
#pragma unroll
        for (int r = 0; r < 4; ++r) pv[r] = f2bf(acc[mf][nf][r] + bv);
        *(short4v*)&vb[((size_t)(b * NH + hh) * HD + dd) * SEQ + n0] = pv;
      } else {
        bf16* dst = (which == 0) ? qb : kb;
        const float sc = (which == 0) ? SCALE_QL2E : 1.0f;
#pragma unroll
        for (int r = 0; r < 4; ++r)
          dst[((size_t)(b * NH + hh) * SEQ + n0 + r) * HD + dd] =
              __float2bfloat16((acc[mf][nf][r] + bv) * sc);
      }
    }
  }
}

// ---------------------------------------------------------------------------
// Kernel 2: flash attention — r4 structure: KVBLK=64, double-buffered K/V,
// one barrier per kv-tile, l-sum via MFMA ones-trick, setprio on MFMA.
// (frozen; 65.5 us = 786 TF eff.)
// ---------------------------------------------------------------------------
__global__ void __launch_bounds__(256, 3)
flash_attn(const bf16* __restrict__ Qp, const bf16* __restrict__ Kp,
           const bf16* __restrict__ Vtp, bf16* __restrict__ Op) {
  const int bh = blockIdx.y, qt = blockIdx.x;
  const int t = threadIdx.x, w = t >> 6, l = t & 63, lr = l & 15, q = l >> 4;
  __shared__ short Ks[2][64 * 68];   // K tile [kk][d], dbuf, pad 64->68
  __shared__ short Vt[2][64 * 66];   // V^T tile [d][kk], dbuf, pad 64->66

  const bf16* Qb = Qp  + (size_t)(bh * SEQ + qt * 128) * HD;
  const bf16* Kb = Kp  + (size_t)bh * SEQ * HD;
  const bf16* Vb = Vtp + (size_t)bh * HD * SEQ;   // [d][n]

  const int tr3 = t >> 3, td8 = (t & 7) * 8;     // 32 rows x 64 cols per pass

  // stage Q [128][64]: rows 0-63 -> Ks[0], rows 64-127 -> Ks[1]
#pragma unroll
  for (int i = 0; i < 4; ++i) {
    const int row = i * 32 + tr3;
    *(short8v*)&Ks[row >> 6][(row & 63) * 68 + td8] =
        *(const short8v*)(Qb + (size_t)row * HD + td8);
  }
  __syncthreads();
  bf16x8 qf[2][2];
#pragma unroll
  for (int it = 0; it < 2; ++it)
#pragma unroll
    for (int kq = 0; kq < 2; ++kq) {
      const int row = w * 32 + it * 16 + lr;
      qf[it][kq] = *(const bf16x8*)&Ks[row >> 6][(row & 63) * 68 + kq * 32 + q * 8];
    }
  __syncthreads();   // all Q frags in regs before kt=0 overwrites Ks[0]

  // prefetch K/V tile 0 into registers
  short8v kr[2], vr[2];
#pragma unroll
  for (int i = 0; i < 2; ++i) {
    kr[i] = *(const short8v*)(Kb + (size_t)(i * 32 + tr3) * HD + td8);
    vr[i] = *(const short8v*)(Vb + (size_t)(i * 32 + tr3) * SEQ + td8);
  }

  frag8 ones;            // all-ones bf16 B-fragment for the l row-sum MFMA
#pragma unroll
  for (int r = 0; r < 8; ++r) ones.s[r] = (short)0x3F80;

  float4v o[2][4] = {};
  float4v lacc[2] = {};  // l, col-replicated in C/D layout

  for (int kt = 0; kt < 32; ++kt) {
    const int cur = kt & 1;
    // write tile kt (regs->LDS); issue prefetch kt+1 (hides under compute)
#pragma unroll
    for (int i = 0; i < 2; ++i) {
      *(short8v*)&Ks[cur][(i * 32 + tr3) * 68 + td8] = kr[i];
      *(short8v*)&Vt[cur][(i * 32 + tr3) * 66 + td8] = vr[i];
    }
    if (kt < 31) {
      const int k1 = (kt + 1) * 64;
#pragma unroll
      for (int i = 0; i < 2; ++i) {
        kr[i] = *(const short8v*)(Kb + (size_t)(k1 + i * 32 + tr3) * HD + td8);
        vr[i] = *(const short8v*)(Vb + (size_t)(i * 32 + tr3) * SEQ + k1 + td8);
      }
    }
    __syncthreads();

    // S^T = K * Q^T : tiles [kk 4][qr 2]
    float4v s[4][2] = {};
    __builtin_amdgcn_s_setprio(1);
#pragma unroll
    for (int jn = 0; jn < 4; ++jn) {
      bf16x8 kf[2];
#pragma unroll
      for (int kq = 0; kq < 2; ++kq)
        kf[kq] = *(const bf16x8*)&Ks[cur][(jn * 16 + lr) * 68 + kq * 32 + q * 8];
#pragma unroll
      for (int it = 0; it < 2; ++it)
#pragma unroll
        for (int kq = 0; kq < 2; ++kq)
          s[jn][it] = __builtin_amdgcn_mfma_f32_16x16x32_bf16(kf[kq], qf[it][kq],
                                                              s[jn][it], 0, 0, 0);
    }
    __builtin_amdgcn_s_setprio(0);

    // p = exp2(s), pack pairs: slot (q,j) <-> kk = 32c + 16*(j>>2) + 4q + (j&3)
    frag8 pf[2][2];
#pragma unroll
    for (int it = 0; it < 2; ++it)
#pragma unroll
      for (int c4 = 0; c4 < 2; ++c4)
#pragma unroll
        for (int r = 0; r < 4; ++r) {
          pf[c4][it].s[r]     = f2bf(__builtin_amdgcn_exp2f(s[2 * c4][it][r]));
          pf[c4][it].s[4 + r] = f2bf(__builtin_amdgcn_exp2f(s[2 * c4 + 1][it][r]));
        }

    // O += P * V ; l += P * 1  (B mirrors the paired-k slot mapping)
    __builtin_amdgcn_s_setprio(1);
#pragma unroll
    for (int c4 = 0; c4 < 2; ++c4) {
#pragma unroll
      for (int dj = 0; dj < 4; ++dj) {
        frag8 vf;
        vf.h[0] = *(const short4v*)&Vt[cur][(dj * 16 + lr) * 66 + c4 * 32 + (q << 2)];
        vf.h[1] = *(const short4v*)&Vt[cur][(dj * 16 + lr) * 66 + c4 * 32 + 16 + (q << 2)];
#pragma unroll
        for (int it = 0; it < 2; ++it)
          o[it][dj] = __builtin_amdgcn_mfma_f32_16x16x32_bf16(pf[c4][it].b, vf.b,
                                                              o[it][dj], 0, 0, 0);
      }
#pragma unroll
      for (int it = 0; it < 2; ++it)
        lacc[it] = __builtin_amdgcn_mfma_f32_16x16x32_bf16(pf[c4][it].b, ones.b,
                                                           lacc[it], 0, 0, 0);
    }
    __builtin_amdgcn_s_setprio(0);
  }

  // epilogue: linv directly per lane (lacc col-replicated), no shuffles
  const int b = bh / NH, h = bh - b * NH;
#pragma unroll
  for (int it = 0; it < 2; ++it)
#pragma unroll
    for (int r = 0; r < 4; ++r) {
      const float linv = 1.0f / lacc[it][r];
      const int grow = b * SEQ + qt * 128 + w * 32 + it * 16 + (q << 2) + r;
      bf16* orow = Op + (size_t)grow * DIM + h * HD;
#pragma unroll
      for (int dj = 0; dj < 4; ++dj)
        orow[dj * 16 + lr] = __float2bfloat16(o[it][dj][r] * linv);
    }
}

// ---------------------------------------------------------------------------
// Kernel 3: output projection.  AO[8192,768](bf16) @ w_proj^T(bf16) + b -> f32
// (unchanged this round)
// ---------------------------------------------------------------------------
__global__ void __launch_bounds__(256)
gemm_proj(const bf16* __restrict__ A, const bf16* __restrict__ W,
          const float* __restrict__ bias, float* __restrict__ out) {
  __shared__ short As[128 * 32];
  __shared__ short Bs[128 * 32];
  const int t = threadIdx.x;
  const int w = t >> 6, l = t & 63, lr = l & 15, q = l >> 4;
  const int wr = ((w >> 1) << 6), wc = ((w & 1) << 6);
  const int row0 = blockIdx.y * 128, col0 = blockIdx.x * 128;

  float4v acc[4][4] = {};
  gemm_mainloop(A + row0 * DIM, W + col0 * DIM, As, Bs, acc);

#pragma unroll
  for (int j = 0; j < 4; ++j) {
    const int gn = col0 + wc + j * 16 + lr;
    const float bv = bias[gn];
#pragma unroll
    for (int i = 0; i < 4; ++i) {
#pragma unroll
      for (int r = 0; r < 4; ++r) {
        const int gm = row0 + wr + i * 16 + (q << 2) + r;
        out[(size_t)gm * DIM + gn] = acc[i][j][r] + bv;
      }
    }
  }
}

// ---------------------------------------------------------------------------
extern "C" void kernel_launch(void* const* d_in, const int* in_sizes, int n_in,
                              void* d_out, int out_size, void* d_ws, size_t ws_size,
                              hipStream_t stream) {
  const float* x      = (const float*)d_in[0];
  const float* w_qkv  = (const float*)d_in[1];
  const float* b_qkv  = (const float*)d_in[2];
  const float* w_proj = (const float*)d_in[3];
  const float* b_proj = (const float*)d_in[4];
  float* out = (float*)d_out;

  const size_t perbuf = (size_t)BATCH * NH * SEQ * HD;  // 6291456 elems
  bf16* qb  = (bf16*)d_ws;
  bf16* kb  = qb + perbuf;
  bf16* vb  = kb + perbuf;          // [B,H,64,N] transposed
  bf16* ao  = vb + perbuf;
  bf16* xb  = ao + perbuf;          // NX
  bf16* wqb = xb + (size_t)NX;      // NWQ
  bf16* wpb = wqb + (size_t)NWQ;    // NWP

  const int cvt_blocks = (NX + NWQ + NWP) / 8 / 256;   // 4224
  cvt3<<<cvt_blocks, 256, 0, stream>>>(x, xb, NX, w_qkv, wqb, NWQ, w_proj, wpb, NWP);
  gemm_qkv <<<dim3(512), 256, 0, stream>>>(xb, wqb, b_qkv, qb, kb, vb);
  flash_attn<<<dim3(SEQ / 128, BATCH * NH), 256, 0, stream>>>(qb, kb, vb, ao);
  gemm_proj <<<dim3(DIM / 128, TOK / 128),  256, 0, stream>>>(ao, wpb, b_proj, out);
}